// Round 4
// baseline (123.905 us; speedup 1.0000x reference)
//
#include <hip/hip_runtime.h>
#include <math.h>

#define BIGF 1e9f

constexpr int BB = 2, CC = 4, DD = 64, HH = 64, WW = 64;
constexpr int HW   = HH * WW;      // 4096
constexpr int DHW  = DD * HW;      // 262144
constexpr int CDHW = CC * DHW;     // 1048576
constexpr int NTOT = BB * CDHW;    // 2097152
constexpr int NBLK_B = 1024;       // (b, h, c, half)

// ---------------------------------------------------------------------------
// Kernel A: W-pass (ballot nearest-set-bit) + H-pass (min-plus), per (b,c,d)
// slice. Writes dsq TRANSPOSED as [b][c][h][d][w] so kernel B's staging read
// is a contiguous 16 KB stream. Also zeroes kernel B's last-block counter.
// ---------------------------------------------------------------------------
__global__ __launch_bounds__(256) void edt_wh(const int* __restrict__ tgt,
                                              float* __restrict__ dsq,
                                              unsigned int* __restrict__ counter) {
    __shared__ int   ti[HW];   // 16 KB targets slice
    __shared__ float fs[HW];   // 16 KB W-pass result
    const int t   = threadIdx.x;
    const int blk = blockIdx.x;
    if (blk == 0 && t == 0)
        __hip_atomic_store(counter, 0u, __ATOMIC_RELAXED, __HIP_MEMORY_SCOPE_AGENT);

    const int lane = t & 63;
    const int wv   = t >> 6;
    const int b = blk >> 8;
    const int c = (blk >> 6) & 3;
    const int d = blk & 63;
    const size_t tb = (size_t)(b * 64 + d) * HW;   // tgt[b][d][:][:]

    #pragma unroll
    for (int k = 0; k < 16; ++k) ti[t + k * 256] = tgt[tb + t + k * 256];
    __syncthreads();

    // W-pass: binary input -> squared distance to nearest lane of class c.
    #pragma unroll
    for (int r = 0; r < 16; ++r) {
        const int h = wv * 16 + r;
        const bool isc = (ti[h * 64 + lane] == c);
        const unsigned long long mask = __ballot(isc);
        const unsigned long long mlo  = mask & (~0ull >> (63 - lane));
        const unsigned long long mhi  = mask & (~0ull << lane);
        int dd = 1000;
        if (mlo) dd = lane - (63 - __builtin_clzll(mlo));
        if (mhi) dd = min(dd, (int)__builtin_ctzll(mhi) - lane);
        fs[h * 64 + lane] = (dd >= 1000) ? BIGF : (float)(dd * dd);
    }
    __syncthreads();

    // H-pass: 4(i) x 4(w) register tile per thread.
    const int wg = (t & 15) * 4;
    const int i0 = (t >> 4) * 4;
    float acc[4][4];
    #pragma unroll
    for (int a = 0; a < 4; ++a)
        #pragma unroll
        for (int k = 0; k < 4; ++k) acc[a][k] = BIGF;

    #pragma unroll 8
    for (int j = 0; j < 64; ++j) {
        const float4 v = *reinterpret_cast<const float4*>(&fs[j * 64 + wg]);
        #pragma unroll
        for (int a = 0; a < 4; ++a) {
            const float diff = (float)(i0 + a - j);
            const float cost = diff * diff;
            acc[a][0] = fminf(acc[a][0], v.x + cost);
            acc[a][1] = fminf(acc[a][1], v.y + cost);
            acc[a][2] = fminf(acc[a][2], v.z + cost);
            acc[a][3] = fminf(acc[a][3], v.w + cost);
        }
    }
    // Transposed write: dsq[b][c][h=i0+a][d][w]
    const size_t cb = (size_t)(b * 4 + c) * DHW;
    #pragma unroll
    for (int a = 0; a < 4; ++a) {
        const float4 o = make_float4(acc[a][0], acc[a][1], acc[a][2], acc[a][3]);
        *reinterpret_cast<float4*>(&dsq[cb + (size_t)(i0 + a) * HW + d * 64 + wg]) = o;
    }
}

// ---------------------------------------------------------------------------
// Kernel B: block = (b, h, c, half). Stages its class slab dsq[b][c][h][:][:]
// (contiguous 16 KB), D min-plus for 32 output rows into registers, fused
// softmax*sqrt reduce directly from registers (no exchange), block partials,
// last-block deterministic final sum. 16 KB LDS -> 4 blocks/CU resident.
// ---------------------------------------------------------------------------
__global__ __launch_bounds__(256) void edt_dc_reduce(const float* __restrict__ pred,
                                                     const float* __restrict__ dsq,
                                                     float* __restrict__ partial,
                                                     unsigned int* __restrict__ counter,
                                                     float* __restrict__ out) {
    __shared__ float sl[HW];   // 16 KB: class slab [d][w]
    __shared__ float wsum[4];
    __shared__ int   lastflag;
    const int t    = threadIdx.x;
    const int blk  = blockIdx.x;
    const int half = blk & 1;
    const int c    = (blk >> 1) & 3;
    const int h    = (blk >> 3) & 63;
    const int b    = blk >> 9;

    // Stage: contiguous 16 KB, batched loads (1 HBM latency, not 4).
    const size_t sbase = (size_t)((b * 4 + c) * 64 + h) * HW;
    float4 stg[4];
    #pragma unroll
    for (int k = 0; k < 4; ++k)
        stg[k] = *reinterpret_cast<const float4*>(&dsq[sbase + (size_t)(k * 256 + t) * 4]);
    #pragma unroll
    for (int k = 0; k < 4; ++k)
        *reinterpret_cast<float4*>(&sl[(k * 256 + t) * 4]) = stg[k];
    __syncthreads();

    // D min-plus: 2(rows) x 4(w) register tile; rows rbase..rbase+1.
    const int wg    = (t & 15) * 4;
    const int rbase = half * 32 + (t >> 4) * 2;
    float acc[2][4];
    #pragma unroll
    for (int a = 0; a < 2; ++a)
        #pragma unroll
        for (int k = 0; k < 4; ++k) acc[a][k] = BIGF;

    #pragma unroll 8
    for (int j = 0; j < 64; ++j) {
        const float4 v = *reinterpret_cast<const float4*>(&sl[j * 64 + wg]);
        #pragma unroll
        for (int a = 0; a < 2; ++a) {
            const float diff = (float)(rbase + a - j);
            const float cost = diff * diff;
            acc[a][0] = fminf(acc[a][0], v.x + cost);
            acc[a][1] = fminf(acc[a][1], v.y + cost);
            acc[a][2] = fminf(acc[a][2], v.z + cost);
            acc[a][3] = fminf(acc[a][3], v.w + cost);
        }
    }

    // Fused reduce: this block contributes e_c * sqrt(d_c) * zinv for its
    // 32x64 points (partials across class-blocks sum to the full dot).
    float vsum = 0.f;
    #pragma unroll
    for (int a = 0; a < 2; ++a) {
        const int d = rbase + a;
        const size_t pb = (size_t)b * CDHW + (size_t)d * HW + h * 64 + wg;
        const float4 q0 = *reinterpret_cast<const float4*>(&pred[pb]);
        const float4 q1 = *reinterpret_cast<const float4*>(&pred[pb + (size_t)DHW]);
        const float4 q2 = *reinterpret_cast<const float4*>(&pred[pb + 2 * (size_t)DHW]);
        const float4 q3 = *reinterpret_cast<const float4*>(&pred[pb + 3 * (size_t)DHW]);
        {   const float m = fmaxf(fmaxf(q0.x, q1.x), fmaxf(q2.x, q3.x));
            const float e0 = __expf(q0.x - m), e1 = __expf(q1.x - m),
                        e2 = __expf(q2.x - m), e3 = __expf(q3.x - m);
            const float zinv = 1.0f / (e0 + e1 + e2 + e3);
            const float es = (c == 0) ? e0 : (c == 1) ? e1 : (c == 2) ? e2 : e3;
            vsum += es * sqrtf(acc[a][0]) * zinv; }
        {   const float m = fmaxf(fmaxf(q0.y, q1.y), fmaxf(q2.y, q3.y));
            const float e0 = __expf(q0.y - m), e1 = __expf(q1.y - m),
                        e2 = __expf(q2.y - m), e3 = __expf(q3.y - m);
            const float zinv = 1.0f / (e0 + e1 + e2 + e3);
            const float es = (c == 0) ? e0 : (c == 1) ? e1 : (c == 2) ? e2 : e3;
            vsum += es * sqrtf(acc[a][1]) * zinv; }
        {   const float m = fmaxf(fmaxf(q0.z, q1.z), fmaxf(q2.z, q3.z));
            const float e0 = __expf(q0.z - m), e1 = __expf(q1.z - m),
                        e2 = __expf(q2.z - m), e3 = __expf(q3.z - m);
            const float zinv = 1.0f / (e0 + e1 + e2 + e3);
            const float es = (c == 0) ? e0 : (c == 1) ? e1 : (c == 2) ? e2 : e3;
            vsum += es * sqrtf(acc[a][2]) * zinv; }
        {   const float m = fmaxf(fmaxf(q0.w, q1.w), fmaxf(q2.w, q3.w));
            const float e0 = __expf(q0.w - m), e1 = __expf(q1.w - m),
                        e2 = __expf(q2.w - m), e3 = __expf(q3.w - m);
            const float zinv = 1.0f / (e0 + e1 + e2 + e3);
            const float es = (c == 0) ? e0 : (c == 1) ? e1 : (c == 2) ? e2 : e3;
            vsum += es * sqrtf(acc[a][3]) * zinv; }
    }

    const int lane = t & 63;
    #pragma unroll
    for (int off = 32; off > 0; off >>= 1) vsum += __shfl_down(vsum, off, 64);
    if (lane == 0) wsum[t >> 6] = vsum;
    __syncthreads();
    if (t == 0) partial[blk] = wsum[0] + wsum[1] + wsum[2] + wsum[3];

    // Last-block deterministic final reduction.
    __threadfence();
    if (t == 0) {
        const unsigned int old = atomicAdd(counter, 1u);
        lastflag = (old == NBLK_B - 1) ? 1 : 0;
    }
    __syncthreads();
    if (lastflag) {
        __threadfence();
        if (t < 64) {
            double s = 0.0;
            #pragma unroll
            for (int k = 0; k < 16; ++k)
                s += (double)__hip_atomic_load(&partial[t + k * 64],
                                               __ATOMIC_RELAXED, __HIP_MEMORY_SCOPE_AGENT);
            #pragma unroll
            for (int off = 32; off > 0; off >>= 1) s += __shfl_down(s, off, 64);
            if (t == 0) out[0] = (float)(s / (double)NTOT);
        }
    }
}

// ---------------------------------------------------------------------------
extern "C" void kernel_launch(void* const* d_in, const int* in_sizes, int n_in,
                              void* d_out, int out_size, void* d_ws, size_t ws_size,
                              hipStream_t stream) {
    const float* pred = (const float*)d_in[0];
    const int*   tgt  = (const int*)d_in[1];
    float* out     = (float*)d_out;
    float* dsq     = (float*)d_ws;                       // NTOT floats (8 MB)
    float* partial = dsq + NTOT;                         // NBLK_B floats
    unsigned int* counter = (unsigned int*)(partial + NBLK_B);

    hipLaunchKernelGGL(edt_wh,        dim3(BB * CC * DD), dim3(256), 0, stream,
                       tgt, dsq, counter);
    hipLaunchKernelGGL(edt_dc_reduce, dim3(NBLK_B),       dim3(256), 0, stream,
                       pred, dsq, partial, counter, out);
}

// Round 5
// 70.691 us; speedup vs baseline: 1.7528x; 1.7528x over previous
//
#include <hip/hip_runtime.h>
#include <math.h>

#define BIGF 1e9f

constexpr int BB = 2, CC = 4, DD = 64, HH = 64, WW = 64;
constexpr int HW   = HH * WW;      // 4096
constexpr int DHW  = DD * HW;      // 262144
constexpr int CDHW = CC * DHW;     // 1048576
constexpr int NTOT = BB * CDHW;    // 2097152
constexpr int NBLK_C = 512;        // reduce grid: one float4 per thread

// ---------------------------------------------------------------------------
// Kernel A (proven in R4): W-pass (ballot nearest-set-bit) + H-pass (min-plus)
// per (b,c,d) slice. Writes dsqT transposed as [b][c][h][d][w] so kernel B's
// staging read is a contiguous 16 KB stream. Zeroes kernel C's counter.
// ---------------------------------------------------------------------------
__global__ __launch_bounds__(256) void edt_wh(const int* __restrict__ tgt,
                                              float* __restrict__ dsqT,
                                              unsigned int* __restrict__ counter) {
    __shared__ int   ti[HW];   // 16 KB targets slice
    __shared__ float fs[HW];   // 16 KB W-pass result
    const int t   = threadIdx.x;
    const int blk = blockIdx.x;
    if (blk == 0 && t == 0)
        __hip_atomic_store(counter, 0u, __ATOMIC_RELAXED, __HIP_MEMORY_SCOPE_AGENT);

    const int lane = t & 63;
    const int wv   = t >> 6;
    const int b = blk >> 8;
    const int c = (blk >> 6) & 3;
    const int d = blk & 63;
    const size_t tb = (size_t)(b * 64 + d) * HW;   // tgt[b][d][:][:]

    #pragma unroll
    for (int k = 0; k < 16; ++k) ti[t + k * 256] = tgt[tb + t + k * 256];
    __syncthreads();

    // W-pass: binary input -> squared distance to nearest lane of class c.
    #pragma unroll
    for (int r = 0; r < 16; ++r) {
        const int h = wv * 16 + r;
        const bool isc = (ti[h * 64 + lane] == c);
        const unsigned long long mask = __ballot(isc);
        const unsigned long long mlo  = mask & (~0ull >> (63 - lane));
        const unsigned long long mhi  = mask & (~0ull << lane);
        int dd = 1000;
        if (mlo) dd = lane - (63 - __builtin_clzll(mlo));
        if (mhi) dd = min(dd, (int)__builtin_ctzll(mhi) - lane);
        fs[h * 64 + lane] = (dd >= 1000) ? BIGF : (float)(dd * dd);
    }
    __syncthreads();

    // H-pass: 4(i) x 4(w) register tile per thread.
    const int wg = (t & 15) * 4;
    const int i0 = (t >> 4) * 4;
    float acc[4][4];
    #pragma unroll
    for (int a = 0; a < 4; ++a)
        #pragma unroll
        for (int k = 0; k < 4; ++k) acc[a][k] = BIGF;

    #pragma unroll 8
    for (int j = 0; j < 64; ++j) {
        const float4 v = *reinterpret_cast<const float4*>(&fs[j * 64 + wg]);
        #pragma unroll
        for (int a = 0; a < 4; ++a) {
            const float diff = (float)(i0 + a - j);
            const float cost = diff * diff;
            acc[a][0] = fminf(acc[a][0], v.x + cost);
            acc[a][1] = fminf(acc[a][1], v.y + cost);
            acc[a][2] = fminf(acc[a][2], v.z + cost);
            acc[a][3] = fminf(acc[a][3], v.w + cost);
        }
    }
    // Transposed write: dsqT[b][c][h=i0+a][d][w]  (fire-and-forget scatter)
    const size_t cb = (size_t)(b * 4 + c) * DHW;
    #pragma unroll
    for (int a = 0; a < 4; ++a) {
        const float4 o = make_float4(acc[a][0], acc[a][1], acc[a][2], acc[a][3]);
        *reinterpret_cast<float4*>(&dsqT[cb + (size_t)(i0 + a) * HW + d * 64 + wg]) = o;
    }
}

// ---------------------------------------------------------------------------
// Kernel B: D-pass per (b,c,h). Reads CONTIGUOUS 16 KB slab [d][w] from dsqT,
// min-plus along d (R1's proven pass_h body), writes result to dsqN in
// pred-native layout [b][c][d][h][w] (scattered 256 B stores).
// ---------------------------------------------------------------------------
__global__ __launch_bounds__(256) void edt_d(const float* __restrict__ dsqT,
                                             float* __restrict__ dsqN) {
    __shared__ float sl[HW];   // 16 KB slab [d][w]
    const int t   = threadIdx.x;
    const int blk = blockIdx.x;      // (b*4+c)*64 + h
    const int h   = blk & 63;
    const int bc  = blk >> 6;

    // Contiguous stage, batched (one latency, not four).
    const size_t sbase = (size_t)blk * HW;
    float4 stg[4];
    #pragma unroll
    for (int k = 0; k < 4; ++k)
        stg[k] = *reinterpret_cast<const float4*>(&dsqT[sbase + (size_t)(k * 256 + t) * 4]);
    #pragma unroll
    for (int k = 0; k < 4; ++k)
        *reinterpret_cast<float4*>(&sl[(k * 256 + t) * 4]) = stg[k];
    __syncthreads();

    // D min-plus: 4(i) x 4(w) register tile per thread.
    const int wg = (t & 15) * 4;
    const int i0 = (t >> 4) * 4;
    float acc[4][4];
    #pragma unroll
    for (int a = 0; a < 4; ++a)
        #pragma unroll
        for (int k = 0; k < 4; ++k) acc[a][k] = BIGF;

    #pragma unroll 8
    for (int j = 0; j < 64; ++j) {
        const float4 v = *reinterpret_cast<const float4*>(&sl[j * 64 + wg]);
        #pragma unroll
        for (int a = 0; a < 4; ++a) {
            const float diff = (float)(i0 + a - j);
            const float cost = diff * diff;
            acc[a][0] = fminf(acc[a][0], v.x + cost);
            acc[a][1] = fminf(acc[a][1], v.y + cost);
            acc[a][2] = fminf(acc[a][2], v.z + cost);
            acc[a][3] = fminf(acc[a][3], v.w + cost);
        }
    }
    // Native-layout write: dsqN[b][c][d=i0+a][h][w]  (fire-and-forget scatter)
    const size_t nb = (size_t)bc * DHW + (size_t)h * 64;
    #pragma unroll
    for (int a = 0; a < 4; ++a) {
        const float4 o = make_float4(acc[a][0], acc[a][1], acc[a][2], acc[a][3]);
        *reinterpret_cast<float4*>(&dsqN[nb + (size_t)(i0 + a) * HW + wg]) = o;
    }
}

// ---------------------------------------------------------------------------
// Kernel C: fused softmax*sqrt reduce. One float4 of spatial points per
// thread; 8 fully-coalesced streams (4 pred + 4 dsqN at 1 MB class stride).
// Block partials + last-block deterministic final sum.
// ---------------------------------------------------------------------------
__global__ __launch_bounds__(256) void bl_reduce(const float* __restrict__ pred,
                                                 const float* __restrict__ dsqN,
                                                 float* __restrict__ partial,
                                                 unsigned int* __restrict__ counter,
                                                 float* __restrict__ out) {
    __shared__ float wsum[4];
    __shared__ int   lastflag;
    const int t   = threadIdx.x;
    const int blk = blockIdx.x;
    const int q   = blk * 256 + t;            // quad index, 0 .. B*DHW/4-1
    const int b   = q >> 16;                  // DHW/4 = 65536
    const size_t p = (size_t)b * CDHW + (size_t)(q & 65535) * 4;

    const float4 q0 = *reinterpret_cast<const float4*>(&pred[p]);
    const float4 q1 = *reinterpret_cast<const float4*>(&pred[p + (size_t)DHW]);
    const float4 q2 = *reinterpret_cast<const float4*>(&pred[p + 2 * (size_t)DHW]);
    const float4 q3 = *reinterpret_cast<const float4*>(&pred[p + 3 * (size_t)DHW]);
    const float4 s0 = *reinterpret_cast<const float4*>(&dsqN[p]);
    const float4 s1 = *reinterpret_cast<const float4*>(&dsqN[p + (size_t)DHW]);
    const float4 s2 = *reinterpret_cast<const float4*>(&dsqN[p + 2 * (size_t)DHW]);
    const float4 s3 = *reinterpret_cast<const float4*>(&dsqN[p + 3 * (size_t)DHW]);

    float vsum = 0.f;
    #define BL_POINT(X)                                                        \
    {   const float m = fmaxf(fmaxf(q0.X, q1.X), fmaxf(q2.X, q3.X));           \
        const float e0 = __expf(q0.X - m), e1 = __expf(q1.X - m),              \
                    e2 = __expf(q2.X - m), e3 = __expf(q3.X - m);              \
        const float zinv = 1.0f / (e0 + e1 + e2 + e3);                         \
        vsum += (e0 * sqrtf(s0.X) + e1 * sqrtf(s1.X) +                         \
                 e2 * sqrtf(s2.X) + e3 * sqrtf(s3.X)) * zinv; }
    BL_POINT(x) BL_POINT(y) BL_POINT(z) BL_POINT(w)
    #undef BL_POINT

    const int lane = t & 63;
    #pragma unroll
    for (int off = 32; off > 0; off >>= 1) vsum += __shfl_down(vsum, off, 64);
    if (lane == 0) wsum[t >> 6] = vsum;
    __syncthreads();
    if (t == 0) partial[blk] = wsum[0] + wsum[1] + wsum[2] + wsum[3];

    // Last-block deterministic final reduction (proven in R4).
    __threadfence();
    if (t == 0) {
        const unsigned int old = atomicAdd(counter, 1u);
        lastflag = (old == NBLK_C - 1) ? 1 : 0;
    }
    __syncthreads();
    if (lastflag) {
        __threadfence();
        if (t < 64) {
            double s = 0.0;
            #pragma unroll
            for (int k = 0; k < 8; ++k)
                s += (double)__hip_atomic_load(&partial[t + k * 64],
                                               __ATOMIC_RELAXED, __HIP_MEMORY_SCOPE_AGENT);
            #pragma unroll
            for (int off = 32; off > 0; off >>= 1) s += __shfl_down(s, off, 64);
            if (t == 0) out[0] = (float)(s / (double)NTOT);
        }
    }
}

// ---------------------------------------------------------------------------
extern "C" void kernel_launch(void* const* d_in, const int* in_sizes, int n_in,
                              void* d_out, int out_size, void* d_ws, size_t ws_size,
                              hipStream_t stream) {
    const float* pred = (const float*)d_in[0];
    const int*   tgt  = (const int*)d_in[1];
    float* out     = (float*)d_out;
    float* dsqT    = (float*)d_ws;                       // NTOT floats (8 MB)
    float* dsqN    = dsqT + NTOT;                        // NTOT floats (8 MB)
    float* partial = dsqN + NTOT;                        // NBLK_C floats
    unsigned int* counter = (unsigned int*)(partial + NBLK_C);

    hipLaunchKernelGGL(edt_wh,    dim3(BB * CC * DD), dim3(256), 0, stream,
                       tgt, dsqT, counter);
    hipLaunchKernelGGL(edt_d,     dim3(BB * CC * HH), dim3(256), 0, stream,
                       dsqT, dsqN);
    hipLaunchKernelGGL(bl_reduce, dim3(NBLK_C),       dim3(256), 0, stream,
                       pred, dsqN, partial, counter, out);
}

// Round 7
// 30.423 us; speedup vs baseline: 4.0728x; 2.3236x over previous
//
#include <hip/hip_runtime.h>
#include <math.h>

#define BIGF 1e9f

constexpr int BB = 2, CC = 4, DD = 64, HH = 64, WW = 64;
constexpr int HW   = HH * WW;      // 4096
constexpr int DHW  = DD * HW;      // 262144
constexpr int CDHW = CC * DHW;     // 1048576
constexpr int NTOT = BB * CDHW;    // 2097152
constexpr int NBLK = 512;

// ---------------------------------------------------------------------------
// Kernel A: per block (b,c,d):
//  (1) W-pass (ballot nearest-set-bit) + H-pass (min-plus) for class c of
//      plane (b,d)  ->  dsqT[b][c][h][d][w]  (transposed, 256B-segment stores)
//  (2) softmax probs for h-quarter [16c,16c+16) of plane (b,d), ALL classes
//      ->  probT[b][cc][h][d][w]. Quarter = 1024 floats = 256 float4 = ONE
//      step for 256 threads (R6 bug was looping 4x -> OOB).
// ---------------------------------------------------------------------------
__global__ __launch_bounds__(256) void edt_wh_prob(const int* __restrict__ tgt,
                                                   const float* __restrict__ pred,
                                                   float* __restrict__ dsqT,
                                                   float* __restrict__ probT) {
    __shared__ int   ti[HW];   // 16 KB targets slice
    __shared__ float fs[HW];   // 16 KB W-pass result
    const int t   = threadIdx.x;
    const int blk = blockIdx.x;
    const int lane = t & 63;
    const int wv   = t >> 6;
    const int b = blk >> 8;
    const int c = (blk >> 6) & 3;
    const int d = blk & 63;
    const size_t tb = (size_t)(b * 64 + d) * HW;   // tgt[b][d][:][:]

    #pragma unroll
    for (int k = 0; k < 16; ++k) ti[t + k * 256] = tgt[tb + t + k * 256];
    __syncthreads();

    // W-pass: binary input -> squared distance to nearest lane of class c.
    #pragma unroll
    for (int r = 0; r < 16; ++r) {
        const int h = wv * 16 + r;
        const bool isc = (ti[h * 64 + lane] == c);
        const unsigned long long mask = __ballot(isc);
        const unsigned long long mlo  = mask & (~0ull >> (63 - lane));
        const unsigned long long mhi  = mask & (~0ull << lane);
        int dd = 1000;
        if (mlo) dd = lane - (63 - __builtin_clzll(mlo));
        if (mhi) dd = min(dd, (int)__builtin_ctzll(mhi) - lane);
        fs[h * 64 + lane] = (dd >= 1000) ? BIGF : (float)(dd * dd);
    }
    __syncthreads();

    // H-pass: 4(i) x 4(w) register tile per thread.
    const int wg = (t & 15) * 4;
    const int i0 = (t >> 4) * 4;
    float acc[4][4];
    #pragma unroll
    for (int a = 0; a < 4; ++a)
        #pragma unroll
        for (int k = 0; k < 4; ++k) acc[a][k] = BIGF;

    #pragma unroll 8
    for (int j = 0; j < 64; ++j) {
        const float4 v = *reinterpret_cast<const float4*>(&fs[j * 64 + wg]);
        #pragma unroll
        for (int a = 0; a < 4; ++a) {
            const float diff = (float)(i0 + a - j);
            const float cost = diff * diff;
            acc[a][0] = fminf(acc[a][0], v.x + cost);
            acc[a][1] = fminf(acc[a][1], v.y + cost);
            acc[a][2] = fminf(acc[a][2], v.z + cost);
            acc[a][3] = fminf(acc[a][3], v.w + cost);
        }
    }
    const size_t cb = (size_t)(b * 4 + c) * DHW;
    #pragma unroll
    for (int a = 0; a < 4; ++a) {
        const float4 o = make_float4(acc[a][0], acc[a][1], acc[a][2], acc[a][3]);
        *reinterpret_cast<float4*>(&dsqT[cb + (size_t)(i0 + a) * HW + d * 64 + wg]) = o;
    }

    // ---- (2) softmax probs, h-quarter [16c, 16c+16) of plane (b,d) ----
    {
        const int hh = c * 16 + (t >> 4);      // 16 rows of this quarter
        const int w0 = (t & 15) * 4;
        const size_t pidx = (size_t)b * CDHW + (size_t)d * HW + (size_t)hh * 64 + w0;
        const float4 q0 = *reinterpret_cast<const float4*>(&pred[pidx]);
        const float4 q1 = *reinterpret_cast<const float4*>(&pred[pidx + (size_t)DHW]);
        const float4 q2 = *reinterpret_cast<const float4*>(&pred[pidx + 2 * (size_t)DHW]);
        const float4 q3 = *reinterpret_cast<const float4*>(&pred[pidx + 3 * (size_t)DHW]);
        float4 o0, o1, o2, o3;
        #define SMAX(X)                                                          \
        {   const float m = fmaxf(fmaxf(q0.X, q1.X), fmaxf(q2.X, q3.X));         \
            const float e0 = __expf(q0.X - m), e1 = __expf(q1.X - m),            \
                        e2 = __expf(q2.X - m), e3 = __expf(q3.X - m);            \
            const float zinv = 1.0f / (e0 + e1 + e2 + e3);                       \
            o0.X = e0 * zinv; o1.X = e1 * zinv;                                  \
            o2.X = e2 * zinv; o3.X = e3 * zinv; }
        SMAX(x) SMAX(y) SMAX(z) SMAX(w)
        #undef SMAX
        const size_t ob = (size_t)b * CDHW + (size_t)hh * HW + d * 64 + w0;
        *reinterpret_cast<float4*>(&probT[ob])                  = o0;
        *reinterpret_cast<float4*>(&probT[ob + (size_t)DHW])    = o1;
        *reinterpret_cast<float4*>(&probT[ob + 2 * (size_t)DHW]) = o2;
        *reinterpret_cast<float4*>(&probT[ob + 3 * (size_t)DHW]) = o3;
    }
}

// ---------------------------------------------------------------------------
// Kernel B: block = (b,c,h) = linear blk. Stages CONTIGUOUS 16 KB slabs of
// dsqT and probT (both at slab index blk), D min-plus in registers, fused
// prob*sqrt reduce, plain-store block partial. No fences, no atomics.
// ---------------------------------------------------------------------------
__global__ __launch_bounds__(256) void edt_d_reduce(const float* __restrict__ dsqT,
                                                    const float* __restrict__ probT,
                                                    float* __restrict__ partial) {
    __shared__ float sdq[HW];   // 16 KB dsq slab [d][w]
    __shared__ float spr[HW];   // 16 KB prob slab [d][w]
    __shared__ float wsum[4];
    const int t   = threadIdx.x;
    const int blk = blockIdx.x;
    const size_t base = (size_t)blk * HW;

    float4 sg[4], pg[4];
    #pragma unroll
    for (int k = 0; k < 4; ++k)
        sg[k] = *reinterpret_cast<const float4*>(&dsqT[base + (size_t)(k * 256 + t) * 4]);
    #pragma unroll
    for (int k = 0; k < 4; ++k)
        pg[k] = *reinterpret_cast<const float4*>(&probT[base + (size_t)(k * 256 + t) * 4]);
    #pragma unroll
    for (int k = 0; k < 4; ++k) {
        *reinterpret_cast<float4*>(&sdq[(k * 256 + t) * 4]) = sg[k];
        *reinterpret_cast<float4*>(&spr[(k * 256 + t) * 4]) = pg[k];
    }
    __syncthreads();

    // D min-plus: 4(i) x 4(w) register tile.
    const int wg = (t & 15) * 4;
    const int i0 = (t >> 4) * 4;
    float acc[4][4];
    #pragma unroll
    for (int a = 0; a < 4; ++a)
        #pragma unroll
        for (int k = 0; k < 4; ++k) acc[a][k] = BIGF;

    #pragma unroll 8
    for (int j = 0; j < 64; ++j) {
        const float4 v = *reinterpret_cast<const float4*>(&sdq[j * 64 + wg]);
        #pragma unroll
        for (int a = 0; a < 4; ++a) {
            const float diff = (float)(i0 + a - j);
            const float cost = diff * diff;
            acc[a][0] = fminf(acc[a][0], v.x + cost);
            acc[a][1] = fminf(acc[a][1], v.y + cost);
            acc[a][2] = fminf(acc[a][2], v.z + cost);
            acc[a][3] = fminf(acc[a][3], v.w + cost);
        }
    }

    // Fused reduce: prob * sqrt(dsq) for this block's 4x4 tile rows.
    float vsum = 0.f;
    #pragma unroll
    for (int a = 0; a < 4; ++a) {
        const float4 pr = *reinterpret_cast<const float4*>(&spr[(i0 + a) * 64 + wg]);
        vsum += pr.x * sqrtf(acc[a][0]) + pr.y * sqrtf(acc[a][1]) +
                pr.z * sqrtf(acc[a][2]) + pr.w * sqrtf(acc[a][3]);
    }
    const int lane = t & 63;
    #pragma unroll
    for (int off = 32; off > 0; off >>= 1) vsum += __shfl_down(vsum, off, 64);
    if (lane == 0) wsum[t >> 6] = vsum;
    __syncthreads();
    if (t == 0) partial[blk] = wsum[0] + wsum[1] + wsum[2] + wsum[3];
}

// ---------------------------------------------------------------------------
// Kernel C: single-block deterministic final sum (proven in R1).
// ---------------------------------------------------------------------------
__global__ __launch_bounds__(256) void bl_final(const float* __restrict__ partial,
                                                float* __restrict__ out) {
    __shared__ double sd[256];
    double s = (double)partial[threadIdx.x] + (double)partial[threadIdx.x + 256];
    sd[threadIdx.x] = s;
    __syncthreads();
    for (int str = 128; str > 0; str >>= 1) {
        if (threadIdx.x < str) sd[threadIdx.x] += sd[threadIdx.x + str];
        __syncthreads();
    }
    if (threadIdx.x == 0) out[0] = (float)(sd[0] / (double)NTOT);
}

// ---------------------------------------------------------------------------
extern "C" void kernel_launch(void* const* d_in, const int* in_sizes, int n_in,
                              void* d_out, int out_size, void* d_ws, size_t ws_size,
                              hipStream_t stream) {
    const float* pred = (const float*)d_in[0];
    const int*   tgt  = (const int*)d_in[1];
    float* out     = (float*)d_out;
    float* dsqT    = (float*)d_ws;            // NTOT floats (8 MB)
    float* probT   = dsqT + NTOT;             // NTOT floats (8 MB)
    float* partial = probT + NTOT;            // NBLK floats

    hipLaunchKernelGGL(edt_wh_prob,  dim3(NBLK), dim3(256), 0, stream,
                       tgt, pred, dsqT, probT);
    hipLaunchKernelGGL(edt_d_reduce, dim3(NBLK), dim3(256), 0, stream,
                       dsqT, probT, partial);
    hipLaunchKernelGGL(bl_final,     dim3(1),    dim3(256), 0, stream,
                       partial, out);
}